// Round 6
// baseline (1727.104 us; speedup 1.0000x reference)
//
#include <hip/hip_runtime.h>

#define TT  64
#define BSZ 512
#define ISZ 512
#define HSZ 1024

typedef short bf16x8 __attribute__((ext_vector_type(8)));
typedef float f32x4 __attribute__((ext_vector_type(4)));
typedef unsigned short u16x8 __attribute__((ext_vector_type(8)));

typedef const __attribute__((address_space(1))) unsigned int* gas_t;
typedef __attribute__((address_space(3))) unsigned int* las_t;

__device__ __forceinline__ unsigned short f2bf(float f) {
    unsigned int u = __float_as_uint(f);
    unsigned int r = u + 0x7FFFu + ((u >> 16) & 1u);   // RNE
    return (unsigned short)(r >> 16);
}

__global__ void cast_f32_to_bf16(const float* __restrict__ in,
                                 unsigned short* __restrict__ out, int n8) {
    int i = blockIdx.x * blockDim.x + threadIdx.x;
    if (i >= n8) return;
    const float4* p = (const float4*)(in + (size_t)i * 8);
    float4 v0 = p[0], v1 = p[1];
    u16x8 o;
    o[0] = f2bf(v0.x); o[1] = f2bf(v0.y); o[2] = f2bf(v0.z); o[3] = f2bf(v0.w);
    o[4] = f2bf(v1.x); o[5] = f2bf(v1.y); o[6] = f2bf(v1.z); o[7] = f2bf(v1.w);
    *(u16x8*)(out + (size_t)i * 8) = o;
}

__global__ void bias_combine(const float* __restrict__ a,
                             const float* __restrict__ b,
                             float* __restrict__ o) {
    int i = blockIdx.x * blockDim.x + threadIdx.x;
    if (i < 4 * HSZ) o[i] = a[i] + b[i];
}

__global__ void zero_arr(int* p, int n) {
    int i = blockIdx.x * blockDim.x + threadIdx.x;
    if (i < n) p[i] = 0;
}

// Persistent LSTM, regular launch: 256 blocks (1/CU via 144KB LDS), 512 threads
// (8 waves = 2/SIMD). Block (mi=bid>>6, ni=bid&63): b-rows [mi*128,+128),
// h-cols [ni*16,+16). W_hh slice (64 rows x 1024) LDS-resident, swizzled.
// 8 waves = 4 b-quarters (q) x 2 K-halves (kh); k-split merged via LDS reduce.
// Cross-step sync: 4 independent 64-block device-scope spin barriers.
__global__ __launch_bounds__(512, 2) void lstm_persist(
    const unsigned short* __restrict__ xb,    // [TT, BSZ, ISZ] bf16
    const unsigned short* __restrict__ Wihb,  // [4096, 512]
    const unsigned short* __restrict__ Whhb,  // [4096, 1024]
    const float* __restrict__ bias,           // [4096]
    float* __restrict__ out,                  // [TT*BSZ + 2*BSZ, HSZ] fp32
    unsigned short* __restrict__ hb0,
    unsigned short* __restrict__ hb1,
    int* __restrict__ arrive)
{
    __shared__ unsigned short WhL[64 * 1024];   // 128 KiB persistent W_hh slice
    __shared__ unsigned short WS[8192];         //  16 KiB: Wih staging / k-reduce

    const int tid  = threadIdx.x;
    const int lane = tid & 63;
    const int wv   = tid >> 6;       // 0..7
    const int q    = wv & 3;         // b-quarter
    const int kh   = wv >> 2;        // K-half
    const int lr   = lane & 15;
    const int kq   = lane >> 4;      // 0..3
    const int bid  = blockIdx.x;
    const int mi   = bid >> 6;
    const int ni   = bid & 63;
    const int b0   = mi * 128;
    const int hc0  = ni * 16;

    // ---------- prologue: stage W_hh slice into LDS, XOR-swizzled ----------
    // LDS row r (= gate*16 + col) holds G slots s^(r&7); read undoes the XOR.
    #pragma unroll
    for (int i = 0; i < 8; ++i) {
        const int r = wv * 8 + i;
        const int grow = (r >> 4) * HSZ + hc0 + (r & 15);
        const int lsw = (lane & 56) | ((lane & 7) ^ (r & 7));
        #pragma unroll
        for (int hf = 0; hf < 2; ++hf) {
            const unsigned short* g = Whhb + (size_t)grow * HSZ + hf * 512 + lsw * 8;
            __builtin_amdgcn_global_load_lds((gas_t)g, (las_t)(WhL + r * 1024 + hf * 512), 16, 0, 0);
        }
    }
    asm volatile("s_waitcnt vmcnt(0)" ::: "memory");
    __syncthreads();

    float bv[4];
    #pragma unroll
    for (int g = 0; g < 4; ++g) bv[g] = bias[g * HSZ + hc0 + lr];

    // ---------- x-projection (k-split): xg_partial = [bias +] x_t @ Wih^T ----------
    // Wih chunk (64r x 32k) LDS-staged dbuf; x fragments direct from global.
    auto x_part = [&](const unsigned short* xt, f32x4 xg[2][4]) {
        #pragma unroll
        for (int m = 0; m < 2; ++m)
            #pragma unroll
            for (int g = 0; g < 4; ++g)
                xg[m][g] = kh ? (f32x4){0.f, 0.f, 0.f, 0.f}
                              : (f32x4){bv[g], bv[g], bv[g], bv[g]};

        const int sub = lane >> 2;                    // 0..15
        const int se  = ((lane & 3) ^ (sub & 3)) * 8; // pre-swizzled src slot
        const unsigned short* xrow0 = xt + (size_t)(b0 + q * 32 + lr) * ISZ + kh * 256 + kq * 8;
        const unsigned short* wsrc  = Wihb + (size_t)(q * HSZ + hc0 + sub) * ISZ + kh * 256 + se;
        unsigned short* wdst = WS + (kh * 2) * 2048 + q * 512;

        // stage(0)
        __builtin_amdgcn_global_load_lds((gas_t)wsrc, (las_t)wdst, 16, 0, 0);
        bf16x8 af[2][2];
        af[0][0] = *(const bf16x8*)(xrow0);
        af[0][1] = *(const bf16x8*)(xrow0 + 16 * ISZ);

        #pragma unroll
        for (int j = 0; j < 8; ++j) {
            const int cur = j & 1;
            if (j < 7) {
                __builtin_amdgcn_global_load_lds(
                    (gas_t)(wsrc + (j + 1) * 32),
                    (las_t)(WS + (kh * 2 + (cur ^ 1)) * 2048 + q * 512), 16, 0, 0);
                af[cur ^ 1][0] = *(const bf16x8*)(xrow0 + (j + 1) * 32);
                af[cur ^ 1][1] = *(const bf16x8*)(xrow0 + 16 * ISZ + (j + 1) * 32);
                asm volatile("s_waitcnt vmcnt(3)" ::: "memory");
            } else {
                asm volatile("s_waitcnt vmcnt(0)" ::: "memory");
            }
            __builtin_amdgcn_sched_barrier(0);
            __builtin_amdgcn_s_barrier();
            const char* Wc = (const char*)WS + (kh * 2 + cur) * 4096;
            #pragma unroll
            for (int g = 0; g < 4; ++g) {
                bf16x8 wf = *(const bf16x8*)(Wc + (g * 16 + lr) * 64 + ((kq ^ (lr & 3)) << 4));
                xg[0][g] = __builtin_amdgcn_mfma_f32_16x16x32_bf16(af[cur][0], wf, xg[0][g], 0, 0, 0);
                xg[1][g] = __builtin_amdgcn_mfma_f32_16x16x32_bf16(af[cur][1], wf, xg[1][g], 0, 0, 0);
            }
            __builtin_amdgcn_s_barrier();
        }
    };

    // ---------- recurrent half-GEMM: acc += h_{t-1}[:, kh*512:+512] @ Whh^T ----------
    auto h_gemm = [&](const unsigned short* hp, f32x4 acc[2][4]) {
        const unsigned short* hrow0 = hp + (size_t)(b0 + q * 32 + lr) * HSZ + kh * 512 + kq * 8;
        const char* WcB = (const char*)WhL;
        #pragma unroll
        for (int c = 0; c < 16; ++c) {
            bf16x8 a0 = *(const bf16x8*)(hrow0 + c * 32);
            bf16x8 a1 = *(const bf16x8*)(hrow0 + 16 * HSZ + c * 32);
            const int slot = (kh * 16 + c) * 4 + kq;
            const int off  = (slot ^ (lr & 7)) << 4;
            #pragma unroll
            for (int g = 0; g < 4; ++g) {
                bf16x8 wf = *(const bf16x8*)(WcB + (g * 16 + lr) * 2048 + off);
                acc[0][g] = __builtin_amdgcn_mfma_f32_16x16x32_bf16(a0, wf, acc[0][g], 0, 0, 0);
                acc[1][g] = __builtin_amdgcn_mfma_f32_16x16x32_bf16(a1, wf, acc[1][g], 0, 0, 0);
            }
        }
    };

    f32x4 xg[2][4];
    f32x4 creg[2];
    creg[0] = (f32x4){0.f, 0.f, 0.f, 0.f};
    creg[1] = (f32x4){0.f, 0.f, 0.f, 0.f};
    x_part(xb, xg);   // xg for t=0

    float* hn = out + (size_t)TT * BSZ * HSZ;
    float* cn = hn + (size_t)BSZ * HSZ;
    const int n = hc0 + lr;
    f32x4* RED = (f32x4*)WS;

    for (int t = 0; t < TT; ++t) {
        f32x4 acc[2][4];
        #pragma unroll
        for (int m = 0; m < 2; ++m)
            #pragma unroll
            for (int g = 0; g < 4; ++g) acc[m][g] = xg[m][g];

        if (t > 0) h_gemm((t & 1) ? hb0 : hb1, acc);

        // ---- merge K-halves: kh=1 partials -> kh=0 waves (2 rounds, 16KB) ----
        {
            const int base = (q & 1) * 512 + lane * 8;
            if (kh == 1 && q < 2) {
                #pragma unroll
                for (int m = 0; m < 2; ++m)
                    #pragma unroll
                    for (int g = 0; g < 4; ++g) RED[base + m * 4 + g] = acc[m][g];
            }
            __syncthreads();
            if (kh == 0 && q < 2) {
                #pragma unroll
                for (int m = 0; m < 2; ++m)
                    #pragma unroll
                    for (int g = 0; g < 4; ++g) acc[m][g] += RED[base + m * 4 + g];
            }
            __syncthreads();
            if (kh == 1 && q >= 2) {
                #pragma unroll
                for (int m = 0; m < 2; ++m)
                    #pragma unroll
                    for (int g = 0; g < 4; ++g) RED[base + m * 4 + g] = acc[m][g];
            }
            __syncthreads();
            if (kh == 0 && q >= 2) {
                #pragma unroll
                for (int m = 0; m < 2; ++m)
                    #pragma unroll
                    for (int g = 0; g < 4; ++g) acc[m][g] += RED[base + m * 4 + g];
            }
        }

        // ---- LSTM pointwise epilogue (kh=0 waves own the full gates) ----
        if (kh == 0) {
            unsigned short* hbn = (t & 1) ? hb1 : hb0;
            float* outt = out + (size_t)t * BSZ * HSZ;
            #pragma unroll
            for (int m = 0; m < 2; ++m) {
                #pragma unroll
                for (int r = 0; r < 4; ++r) {
                    const int b = b0 + q * 32 + m * 16 + kq * 4 + r;
                    const size_t idx = (size_t)b * HSZ + n;
                    float gi = acc[0 * 2 + m][0][r];  // placeholder keeps indexing clear
                    gi = acc[m][0][r];
                    float gf = acc[m][1][r];
                    float gg = acc[m][2][r];
                    float go = acc[m][3][r];
                    float ig = 1.f / (1.f + __expf(-gi));
                    float fg = 1.f / (1.f + __expf(-gf));
                    float gv = 1.f - 2.f / (__expf(2.f * gg) + 1.f);
                    float og = 1.f / (1.f + __expf(-go));
                    float cnew = fg * creg[m][r] + ig * gv;
                    float hv = og * (1.f - 2.f / (__expf(2.f * cnew) + 1.f));
                    creg[m][r] = cnew;
                    outt[idx] = hv;
                    hbn[idx] = f2bf(hv);
                    if (t == TT - 1) { hn[idx] = hv; cn[idx] = cnew; }
                }
            }
        }

        if (t + 1 < TT) {
            __syncthreads();   // drain epilogue stores; protect WS reuse
            int* ctr = arrive + (size_t)t * 128 + mi * 32;
            if (tid == 0) {
                __threadfence();
                atomicAdd(ctr, 1);
            }
            x_part(xb + (size_t)(t + 1) * BSZ * ISZ, xg);   // overlap with barrier
            if (tid == 0) {
                while (__hip_atomic_load(ctr, __ATOMIC_ACQUIRE, __HIP_MEMORY_SCOPE_AGENT) < 64)
                    __builtin_amdgcn_s_sleep(2);
            }
            __syncthreads();
        }
    }
}

extern "C" void kernel_launch(void* const* d_in, const int* in_sizes, int n_in,
                              void* d_out, int out_size, void* d_ws, size_t ws_size,
                              hipStream_t stream) {
    const float* input_ = (const float*)d_in[0];
    const float* Wih = (const float*)d_in[3];
    const float* Whh = (const float*)d_in[4];
    const float* bih = (const float*)d_in[5];
    const float* bhh = (const float*)d_in[6];

    char* ws = (char*)d_ws;
    unsigned short* Wihb = (unsigned short*)(ws);                 //  4 MB
    unsigned short* Whhb = (unsigned short*)(ws + (4u << 20));    //  8 MB
    unsigned short* xb   = (unsigned short*)(ws + (12u << 20));   // 32 MB
    float*          bias = (float*)(ws + (46u << 20));            // 16 KB
    int*            arr  = (int*)(ws + (47u << 20));              // 32 KB
    unsigned short* hbuf0 = (unsigned short*)(ws + (48u << 20));  //  1 MB
    unsigned short* hbuf1 = (unsigned short*)(ws + (49u << 20));  //  1 MB

    zero_arr<<<32, 256, 0, stream>>>(arr, 64 * 128);
    cast_f32_to_bf16<<<1024, 256, 0, stream>>>(Wih, Wihb, (4 * HSZ * ISZ) / 8);
    cast_f32_to_bf16<<<2048, 256, 0, stream>>>(Whh, Whhb, (4 * HSZ * HSZ) / 8);
    cast_f32_to_bf16<<<8192, 256, 0, stream>>>(input_, xb, (TT * BSZ * ISZ) / 8);
    bias_combine<<<16, 256, 0, stream>>>(bih, bhh, bias);

    float* out = (float*)d_out;
    lstm_persist<<<256, 512, 0, stream>>>(xb, Wihb, Whhb, bias, out,
                                          hbuf0, hbuf1, arr);
}